// Round 21
// baseline (108.434 us; speedup 1.0000x reference)
//
#include <hip/hip_runtime.h>
#include <stdint.h>

#define Bb 2
#define Ss 2048
#define Dd 1024
#define Hh 16
#define HDd 64
// M = B*S = 4096

typedef float f32x4 __attribute__((ext_vector_type(4)));
typedef __bf16 bf16x8 __attribute__((ext_vector_type(8)));
typedef __bf16 bf16x2 __attribute__((ext_vector_type(2)));
typedef short s16x8 __attribute__((ext_vector_type(8)));

__device__ inline unsigned short f2bf(float f) {
  unsigned u = __builtin_bit_cast(unsigned, f);
  u += 0x7fffu + ((u >> 16) & 1u);
  return (unsigned short)(u >> 16);
}
__device__ inline float bf2f(unsigned short h) {
  unsigned u = ((unsigned)h) << 16;
  return __builtin_bit_cast(float, u);
}
// native-cast pair pack: compiler fuses to v_cvt_pk_bf16_f32 (RNE)
__device__ inline unsigned pkcvt(float a, float b) {
  bf16x2 v;
  v[0] = (__bf16)a;
  v[1] = (__bf16)b;
  return __builtin_bit_cast(unsigned, v);
}
// native v_exp_f32 (2^x); avoid OCML precise exp2 path
__device__ inline float ex2(float x) {
#if __has_builtin(__builtin_amdgcn_exp2f)
  return __builtin_amdgcn_exp2f(x);
#else
  float r;
  asm("v_exp_f32 %0, %1\n\ts_nop 1" : "=v"(r) : "v"(x));
  return r;
#endif
}
// XOR-swizzled short-index into a [rows][64-short] LDS tile (attn).
__device__ inline int swz(int row, int soff) {
  return (row << 6) + ((((soff >> 3) ^ (row & 7)) << 3) | (soff & 7));
}

#define GLDS(dst, src)                                                        \
  __builtin_amdgcn_global_load_lds(                                           \
      (const __attribute__((address_space(1))) void*)(src),                   \
      (__attribute__((address_space(3))) void*)(dst), 16, 0, 0)

// ---------------- fused cast fp32 -> bf16 (x, w_qkv, w_dense) ----------------
__global__ void cast_all(const float* __restrict__ x, const float* __restrict__ wq,
                         const float* __restrict__ wd, unsigned short* __restrict__ dst) {
  int i = blockIdx.x * blockDim.x + threadIdx.x;  // float4 units
  float4 v;
  if (i < 1048576) v = ((const float4*)x)[i];
  else if (i < 1835008) v = ((const float4*)wq)[i - 1048576];
  else v = ((const float4*)wd)[i - 1835008];
  ushort4 o;
  o.x = f2bf(v.x); o.y = f2bf(v.y); o.z = f2bf(v.z); o.w = f2bf(v.w);
  ((ushort4*)dst)[i] = o;
}

// ---------------- GEMM1 fused: 128x192 tile, BK=64, 512 thr = 8 waves -------
// r17's verified-best form (35 us): 512 blocks x 80KB dbuf LDS = 2 blocks/CU
// (4 waves/SIMD), one barrier per K-tile, swizzled LDS (0 conflicts),
// VGPR 92 at (512,2) -> no spill. Fused epilogue: rope(q,k); v -> vt.
__global__ __launch_bounds__(512, 2) void gemm_qkv(
    const unsigned short* __restrict__ A, const unsigned short* __restrict__ Bw,
    const float* __restrict__ bias, unsigned short* __restrict__ qkvout,
    unsigned short* __restrict__ vtout,
    const float* __restrict__ fc, const float* __restrict__ fs) {
  const int K = 1024, NT = 16;
  __shared__ __align__(16) unsigned short Ah[2][2][128 * 32];  // 32 KB
  __shared__ __align__(16) unsigned short Bh[2][2][192 * 32];  // 48 KB
  const int tid = threadIdx.x;
  const int w = tid >> 6, l = tid & 63;
  const int lg = l >> 4, lr = l & 15;
  const int wm = w >> 2, wn = w & 3;          // 2m x 4n wave grid
  // XCD-bijective swizzle (nwg = 512, % 8 == 0)
  int id = blockIdx.y * gridDim.x + blockIdx.x;
  const int nwg = gridDim.x * gridDim.y;
  id = (id & 7) * (nwg >> 3) + (id >> 3);
  const int bx = id % gridDim.x, by = id / gridDim.x;
  const int mbase = by * 128, nbase = bx * 192;

  const unsigned short *as0, *bs0, *bs1, *bs2;
  {
    int r_ = tid >> 2, s_ = (tid & 3) ^ ((r_ >> 1) & 3);
    as0 = A + (size_t)(mbase + r_) * K + s_ * 8;
    bs0 = Bw + (size_t)(nbase + r_) * K + s_ * 8;
    int cb2 = 512 + tid;
    int h2 = cb2 >= 768;
    int cw2 = cb2 - h2 * 768;
    int r2 = cw2 >> 2, s2 = (cw2 & 3) ^ ((r2 >> 1) & 3);
    bs1 = Bw + (size_t)(nbase + r2) * K + h2 * 32 + s2 * 8;
    int cw3 = 256 + tid;
    int r3 = cw3 >> 2, s3 = (cw3 & 3) ^ ((r3 >> 1) & 3);
    bs2 = Bw + (size_t)(nbase + r3) * K + 32 + s3 * 8;
  }
#define STAGE(buf, k0)                                                        \
  GLDS(&Ah[buf][0][0] + tid * 8, as0 + (k0));                                 \
  GLDS(&Ah[buf][0][0] + 4096 + tid * 8, as0 + 32 + (k0));                     \
  GLDS(&Bh[buf][0][0] + tid * 8, bs0 + (k0));                                 \
  GLDS(&Bh[buf][0][0] + (512 + tid) * 8, bs1 + (k0));                         \
  GLDS(&Bh[buf][0][0] + (1024 + tid) * 8, bs2 + (k0));

  STAGE(0, 0);
  __syncthreads();

  f32x4 acc[4][3] = {};
  for (int t = 0; t < NT; ++t) {
    const int cur = t & 1;
    if (t + 1 < NT) { STAGE(cur ^ 1, (t + 1) * 64); }
#pragma unroll
    for (int h = 0; h < 2; ++h) {
      bf16x8 bfr[3], af[4];
#pragma unroll
      for (int ni = 0; ni < 3; ++ni) {
        int row = wn * 48 + ni * 16 + lr;
        bfr[ni] = *(const bf16x8*)(&Bh[cur][h][row * 32 + ((lg ^ ((row >> 1) & 3)) << 3)]);
      }
#pragma unroll
      for (int j = 0; j < 4; ++j) {
        int row = wm * 64 + j * 16 + lr;
        af[j] = *(const bf16x8*)(&Ah[cur][h][row * 32 + ((lg ^ ((row >> 1) & 3)) << 3)]);
      }
      __builtin_amdgcn_s_setprio(1);
#pragma unroll
      for (int j = 0; j < 4; ++j)
#pragma unroll
        for (int ni = 0; ni < 3; ++ni)
          acc[j][ni] = __builtin_amdgcn_mfma_f32_16x16x32_bf16(
              af[j], bfr[ni], acc[j][ni], 0, 0, 0);
      __builtin_amdgcn_s_setprio(0);
    }
    __syncthreads();
  }
#undef STAGE

  // ---------------- fused epilogue ----------------
#pragma unroll
  for (int mi = 0; mi < 4; ++mi)
#pragma unroll
    for (int ni = 0; ni < 3; ++ni) {
      int col = nbase + wn * 48 + ni * 16 + lr;
      float bi = bias[col];
      int row0 = mbase + wm * 64 + mi * 16 + lg * 4;
      float o4[4];
#pragma unroll
      for (int r = 0; r < 4; ++r) o4[r] = acc[mi][ni][r] + bi;
      int sect = col >> 10;
      int d = col & 63;
      int srow0 = row0 & 2047;
      if (sect < 2) {
        int p = d >> 1;
#pragma unroll
        for (int r = 0; r < 4; ++r) {
          float vp = __shfl_xor(o4[r], 1);
          float c = fc[(srow0 + r) * 32 + p];
          float s = fs[(srow0 + r) * 32 + p];
          float o = (d & 1) ? (vp * s + o4[r] * c) : (o4[r] * c - vp * s);
          qkvout[(size_t)(row0 + r) * 3072 + col] = f2bf(o);
        }
      } else {
        int bh = (row0 >> 11) * 16 + ((col >> 6) & 15);
        uint2 o;
        o.x = pkcvt(o4[0], o4[1]);
        o.y = pkcvt(o4[2], o4[3]);
        *(uint2*)&vtout[((size_t)(bh * 64 + d)) * 2048 + srow0] = o;
      }
    }
}

// ---------------- GEMM2: 64x128 tile, BK=32, 256 thr = 4 waves (2m x 2n) ----
// 512 blocks (grid 8x64) = 2 blocks/CU: TLP hides the stage drain. Swizzled
// LDS (pre-swizzled global src + linear GLDS dst + swizzled reads).
__global__ __launch_bounds__(256, 2) void gemm_out(
    const unsigned short* __restrict__ A, const unsigned short* __restrict__ Bw,
    const float* __restrict__ bias, float* __restrict__ Cout) {
  const int M = 4096, N = 1024, K = 1024;
  __shared__ __align__(16) unsigned short As[64 * 32];    // 4 KB
  __shared__ __align__(16) unsigned short Bs[128 * 32];   // 8 KB
  const int tid = threadIdx.x;
  const int w = tid >> 6, l = tid & 63;
  const int lg = l >> 4, lr = l & 15;
  const int wm = w >> 1, wn = w & 1;
  // XCD-bijective swizzle (512 blocks, % 8 == 0)
  int id = blockIdx.y * gridDim.x + blockIdx.x;
  const int nwg = gridDim.x * gridDim.y;
  id = (id & 7) * (nwg >> 3) + (id >> 3);
  const int bx = id % gridDim.x, by = id / gridDim.x;
  const int mbase = by * 64, nbase = bx * 128;

  const unsigned short *as0, *bs0, *bs1;
  {
    int r_ = tid >> 2, s_ = (tid & 3) ^ ((r_ >> 1) & 3);
    as0 = A + (size_t)(mbase + r_) * K + s_ * 8;
    bs0 = Bw + (size_t)(nbase + r_) * K + s_ * 8;
    int r2 = 64 + r_, s2 = (tid & 3) ^ ((r2 >> 1) & 3);
    bs1 = Bw + (size_t)(nbase + r2) * K + s2 * 8;
  }

  f32x4 acc[2][4] = {};
  for (int k0 = 0; k0 < K; k0 += 32) {
    GLDS(As + tid * 8, as0 + k0);
    GLDS(Bs + tid * 8, bs0 + k0);
    GLDS(Bs + (256 + tid) * 8, bs1 + k0);
    __syncthreads();
    bf16x8 af[2], bfr[4];
#pragma unroll
    for (int mi = 0; mi < 2; ++mi) {
      int row = wm * 32 + mi * 16 + lr;
      af[mi] = *(const bf16x8*)(As + row * 32 + ((lg ^ ((row >> 1) & 3)) << 3));
    }
#pragma unroll
    for (int ni = 0; ni < 4; ++ni) {
      int row = wn * 64 + ni * 16 + lr;
      bfr[ni] = *(const bf16x8*)(Bs + row * 32 + ((lg ^ ((row >> 1) & 3)) << 3));
    }
    __builtin_amdgcn_s_setprio(1);
#pragma unroll
    for (int mi = 0; mi < 2; ++mi)
#pragma unroll
      for (int ni = 0; ni < 4; ++ni)
        acc[mi][ni] = __builtin_amdgcn_mfma_f32_16x16x32_bf16(
            af[mi], bfr[ni], acc[mi][ni], 0, 0, 0);
    __builtin_amdgcn_s_setprio(0);
    __syncthreads();
  }

#pragma unroll
  for (int mi = 0; mi < 2; ++mi) {
#pragma unroll
    for (int ni = 0; ni < 4; ++ni) {
      int col = nbase + wn * 64 + ni * 16 + lr;
      float bi = bias[col];
#pragma unroll
      for (int r = 0; r < 4; ++r) {
        int row = mbase + wm * 32 + mi * 16 + lg * 4 + r;
        Cout[(size_t)row * N + col] = acc[mi][ni][r] + bi;
      }
    }
  }
}

// ---------------- Flash attention (causal), split-K swapped form ----------------
// Block = (bh, 64 q-rows), 4 waves = 2 q-groups x 2 k-slices. V is NOT LDS-
// staged (m169 precedent: per-XCD V working set = 1MB, L2-resident via the
// bh-grouped XCD map) -> va A-fragments read straight from vt (16B/lane,
// L2 hit, TLP-hidden). LDS = Ks dbuf 16KB + Ps 16KB = 32KB -> up to 5
// blocks/CU. Combine scratch reuses Ks (4096 floats exactly) + Ps.
__global__ __launch_bounds__(256, 3) void attn(
    const unsigned short* __restrict__ qkv, const unsigned short* __restrict__ vt,
    unsigned short* __restrict__ ctx) {
  __shared__ __align__(16) unsigned short Ks[2][64 * 64];   // 16 KB
  __shared__ __align__(16) unsigned short Ps[4][32 * 64];   // 16 KB
  int did = blockIdx.x;                  // 1024 blocks
  int x = did & 7, rest = did >> 3;      // XCD x owns bh 4x..4x+3
  int bh = x * 4 + (rest & 3);
  int qi = 31 - (rest >> 2);             // LPT: heavy q-tiles first
  int b = bh >> 4, h = bh & 15;
  int qbase = qi * 64;
  int tid = threadIdx.x;
  int w = tid >> 6, l = tid & 63;
  int lg = l >> 4, lr = l & 15;
  int wq = w & 1, wk = w >> 1;
  int qw = wq * 32;                      // wave's local q base

  // Q fragments for q-rows qbase + qw + mi*16 + lr, log2-domain pre-scale
  bf16x8 qb[2][2];
#pragma unroll
  for (int mi = 0; mi < 2; ++mi)
#pragma unroll
    for (int kc = 0; kc < 2; ++kc) {
      s16x8 qr = *(const s16x8*)(qkv +
          (size_t)(b * Ss + qbase + qw + mi * 16 + lr) * 3072 + h * 64 + kc * 32 + lg * 8);
      bf16x8 qs;
#pragma unroll
      for (int e = 0; e < 8; ++e)
        qs[e] = (__bf16)(bf2f((unsigned short)qr[e]) * 0.18033688f);
      qb[mi][kc] = qs;
    }

  // K staging via GLDS: chunks c1=tid, c2=256+tid; pre-swizzled global src.
  int c1 = tid, c2 = 256 + tid;
  int r1 = c1 >> 3, s1 = ((c1 & 7) ^ (r1 & 7)) * 8;
  int r2 = c2 >> 3, s2 = ((c2 & 7) ^ (r2 & 7)) * 8;
  const unsigned short* kg1 = qkv + ((size_t)(b * Ss) + r1) * 3072 + 1024 + h * 64 + s1;
  const unsigned short* kg2 = qkv + ((size_t)(b * Ss) + r2) * 3072 + 1024 + h * 64 + s2;
  // V^T panel base for direct global fragment reads
  const unsigned short* vtb = vt + (size_t)bh * 64 * 2048;
#define STAGEK(kt)                                                            \
  {                                                                           \
    int tt_ = (kt) & 1;                                                       \
    GLDS(&Ks[tt_][0] + c1 * 8, kg1 + (size_t)(kt) * 64 * 3072);               \
    GLDS(&Ks[tt_][0] + c2 * 8, kg2 + (size_t)(kt) * 64 * 3072);               \
  }

  int nkt = qi + 1;
  int nsup = (nkt + 1) >> 1;

  STAGEK(0);
  if (1 < nkt) STAGEK(1);
  __syncthreads();

  f32x4 acc[4][2] = {};       // ctx^T partial: acc[nd][mi], rows d, cols q(=lr)
  float mrow[2] = {-1e30f, -1e30f}, lsum[2] = {0.f, 0.f};

  for (int j = 0; j < nsup; ++j) {
    int kt = 2 * j + wk;
    if (kt < nkt) {
      // S^T = K Q^T (log2-scaled); ka shared across mi
      f32x4 st[4][2] = {};
      __builtin_amdgcn_s_setprio(1);
#pragma unroll
      for (int kc = 0; kc < 2; ++kc) {
#pragma unroll
        for (int ni = 0; ni < 4; ++ni) {
          bf16x8 ka = *(const bf16x8*)&Ks[wk][swz(ni * 16 + lr, kc * 32 + lg * 8)];
#pragma unroll
          for (int mi = 0; mi < 2; ++mi)
            st[ni][mi] = __builtin_amdgcn_mfma_f32_16x16x32_bf16(
                ka, qb[mi][kc], st[ni][mi], 0, 0, 0);
        }
      }
      __builtin_amdgcn_s_setprio(0);
      // issue V^T fragment loads early (L2-resident; latency hides under softmax)
      bf16x8 va[2][4];
#pragma unroll
      for (int kc = 0; kc < 2; ++kc)
#pragma unroll
        for (int nd = 0; nd < 4; ++nd)
          va[kc][nd] = *(const bf16x8*)&vtb[(size_t)(nd * 16 + lr) * 2048 +
                                            kt * 64 + kc * 32 + lg * 8];

      float tm[2] = {-1e30f, -1e30f};
      if (kt == qi) {               // diagonal tile: causal mask
#pragma unroll
        for (int mi = 0; mi < 2; ++mi) {
          int rq = qw + mi * 16 + lr;
#pragma unroll
          for (int ni = 0; ni < 4; ++ni)
#pragma unroll
            for (int r4 = 0; r4 < 4; ++r4) {
              float s = st[ni][mi][r4];
              if (ni * 16 + lg * 4 + r4 > rq) s = -1e30f;
              st[ni][mi][r4] = s;
              tm[mi] = fmaxf(tm[mi], s);
            }
        }
      } else {
#pragma unroll
        for (int mi = 0; mi < 2; ++mi)
#pragma unroll
          for (int ni = 0; ni < 4; ++ni)
#pragma unroll
            for (int r4 = 0; r4 < 4; ++r4) tm[mi] = fmaxf(tm[mi], st[ni][mi][r4]);
      }
      // defer-max: cross-lane reduce + rescale only when bound trips
      bool ok = (tm[0] <= mrow[0] + 8.0f) && (tm[1] <= mrow[1] + 8.0f);
      if (!__all(ok)) {
#pragma unroll
        for (int mi = 0; mi < 2; ++mi) {
          float t = fmaxf(tm[mi], __shfl_xor(tm[mi], 16));
          t = fmaxf(t, __shfl_xor(t, 32));
          float mnew = fmaxf(mrow[mi], t);
          float alpha = ex2(mrow[mi] - mnew);
          lsum[mi] *= alpha;
#pragma unroll
          for (int nd = 0; nd < 4; ++nd)
#pragma unroll
            for (int r4 = 0; r4 < 4; ++r4) acc[nd][mi][r4] *= alpha;
          mrow[mi] = mnew;
        }
      }
#pragma unroll
      for (int mi = 0; mi < 2; ++mi) {
        float sum = 0.f;
#pragma unroll
        for (int ni = 0; ni < 4; ++ni)
#pragma unroll
          for (int r4 = 0; r4 < 4; ++r4) {
            float pe = ex2(st[ni][mi][r4] - mrow[mi]);
            st[ni][mi][r4] = pe;
            sum += pe;
          }
        lsum[mi] += sum;
        // P[q][k] -> per-wave LDS (swizzled)
#pragma unroll
        for (int ni = 0; ni < 4; ++ni) {
          uint2 wv;
          wv.x = pkcvt(st[ni][mi][0], st[ni][mi][1]);
          wv.y = pkcvt(st[ni][mi][2], st[ni][mi][3]);
          *(uint2*)&Ps[w][swz(mi * 16 + lr, ni * 16 + lg * 4)] = wv;
        }
      }
      // ctx^T += V^T P^T ; va from global (L2), shared across mi
      __builtin_amdgcn_s_setprio(1);
#pragma unroll
      for (int kc = 0; kc < 2; ++kc) {
        bf16x8 pbf[2];
#pragma unroll
        for (int mi = 0; mi < 2; ++mi)
          pbf[mi] = *(const bf16x8*)&Ps[w][swz(mi * 16 + lr, kc * 32 + lg * 8)];
#pragma unroll
        for (int nd = 0; nd < 4; ++nd) {
#pragma unroll
          for (int mi = 0; mi < 2; ++mi)
            acc[nd][mi] = __builtin_amdgcn_mfma_f32_16x16x32_bf16(
                va[kc][nd], pbf[mi], acc[nd][mi], 0, 0, 0);
        }
      }
      __builtin_amdgcn_s_setprio(0);
    }

    if (j + 1 < nsup) {
      __syncthreads();              // all waves done reading K pair j
      int t0 = 2 * (j + 1), t1 = t0 + 1;
      STAGEK(t0);
      if (t1 < nkt) STAGEK(t1);
      __syncthreads();              // GLDS drained (compiler vmcnt0 at barrier)
    }
  }
#undef STAGEK

  // ---- combine the two k-slices of each q-group ----
#pragma unroll
  for (int mi = 0; mi < 2; ++mi) {
    lsum[mi] += __shfl_xor(lsum[mi], 16);
    lsum[mi] += __shfl_xor(lsum[mi], 32);
  }
  __syncthreads();                  // done with Ks; reuse as scratch
  float* aS0 = (float*)&Ks[0][0];   // [2 wq][64 l][16] f32 = 8KB (mi=0)
  float* aS1 = (float*)&Ks[1][0];   // mi=1 (8KB)
  float* mlS = (float*)&Ps[0][0];   // [2 wq][64 l][4]
  if (wk == 1) {
    int base = (wq * 64 + l) * 16;
#pragma unroll
    for (int nd = 0; nd < 4; ++nd) {
      *(f32x4*)(aS0 + base + nd * 4) = acc[nd][0];
      *(f32x4*)(aS1 + base + nd * 4) = acc[nd][1];
    }
    int mb = (wq * 64 + l) * 4;
    mlS[mb] = mrow[0]; mlS[mb + 1] = lsum[0];
    mlS[mb + 2] = mrow[1]; mlS[mb + 3] = lsum[1];
  }
  __syncthreads();
  if (wk == 0) {
    int base = (wq * 64 + l) * 16;
    int mb = (wq * 64 + l) * 4;
#pragma unroll
    for (int mi = 0; mi < 2; ++mi) {
      const float* as = (mi ? aS1 : aS0) + base;
      float m1 = mlS[mb + mi * 2], l1 = mlS[mb + mi * 2 + 1];
      float M = fmaxf(mrow[mi], m1);
      float s0 = ex2(mrow[mi] - M), s1 = ex2(m1 - M);
      float inv = 1.0f / (lsum[mi] * s0 + l1 * s1);
      float f0 = s0 * inv, f1 = s1 * inv;
      int qg = qbase + qw + mi * 16 + lr;
#pragma unroll
      for (int nd = 0; nd < 4; ++nd) {
        f32x4 a1 = *(const f32x4*)(as + nd * 4);
        uint2 o;
        o.x = pkcvt(acc[nd][mi][0] * f0 + a1[0] * f1,
                    acc[nd][mi][1] * f0 + a1[1] * f1);
        o.y = pkcvt(acc[nd][mi][2] * f0 + a1[2] * f1,
                    acc[nd][mi][3] * f0 + a1[3] * f1);
        *(uint2*)&ctx[((size_t)(b * Ss) + qg) * 1024 + h * 64 + nd * 16 + lg * 4] = o;
      }
    }
  }
}

extern "C" void kernel_launch(void* const* d_in, const int* in_sizes, int n_in,
                              void* d_out, int out_size, void* d_ws, size_t ws_size,
                              hipStream_t stream) {
  const float* x       = (const float*)d_in[0];
  const float* w_qkv   = (const float*)d_in[1];
  const float* b_qkv   = (const float*)d_in[2];
  const float* w_dense = (const float*)d_in[3];
  const float* b_dense = (const float*)d_in[4];
  const float* fc      = (const float*)d_in[5];
  const float* fs      = (const float*)d_in[6];
  float* out = (float*)d_out;

  char* ws = (char*)d_ws;
  unsigned short* xb    = (unsigned short*)(ws);                        // 8 MB
  unsigned short* wqkvb = (unsigned short*)(ws + (8ull  << 20));        // 6 MB
  unsigned short* wdb   = (unsigned short*)(ws + (14ull << 20));        // 2 MB
  unsigned short* qkvb  = (unsigned short*)(ws + (16ull << 20));        // 24 MB
  unsigned short* vt    = (unsigned short*)(ws + (40ull << 20));        // 8 MB

  cast_all<<<8192, 256, 0, stream>>>(x, w_qkv, w_dense, xb);

  // GEMM1 fused (128x192 tiles -> 512 blocks = 2/CU, 8 waves, dbuf):
  // rope(q,k) -> qkvb ; v -> vt (transposed)
  gemm_qkv<<<dim3(16, 32), 512, 0, stream>>>(xb, wqkvb, b_qkv, qkvb, vt, fc, fs);
  attn<<<1024, 256, 0, stream>>>(qkvb, vt, xb /* ctx reuse */);
  gemm_out<<<dim3(8, 64), 256, 0, stream>>>(xb, wdb, b_dense, out);
}

// Round 22
// 96.512 us; speedup vs baseline: 1.1235x; 1.1235x over previous
//
#include <hip/hip_runtime.h>
#include <stdint.h>

#define Bb 2
#define Ss 2048
#define Dd 1024
#define Hh 16
#define HDd 64
// M = B*S = 4096

typedef float f32x4 __attribute__((ext_vector_type(4)));
typedef __bf16 bf16x8 __attribute__((ext_vector_type(8)));
typedef __bf16 bf16x2 __attribute__((ext_vector_type(2)));
typedef short s16x8 __attribute__((ext_vector_type(8)));

__device__ inline unsigned short f2bf(float f) {
  unsigned u = __builtin_bit_cast(unsigned, f);
  u += 0x7fffu + ((u >> 16) & 1u);
  return (unsigned short)(u >> 16);
}
__device__ inline float bf2f(unsigned short h) {
  unsigned u = ((unsigned)h) << 16;
  return __builtin_bit_cast(float, u);
}
// native-cast pair pack: compiler fuses to v_cvt_pk_bf16_f32 (RNE)
__device__ inline unsigned pkcvt(float a, float b) {
  bf16x2 v;
  v[0] = (__bf16)a;
  v[1] = (__bf16)b;
  return __builtin_bit_cast(unsigned, v);
}
// native v_exp_f32 (2^x); avoid OCML precise exp2 path
__device__ inline float ex2(float x) {
#if __has_builtin(__builtin_amdgcn_exp2f)
  return __builtin_amdgcn_exp2f(x);
#else
  float r;
  asm("v_exp_f32 %0, %1\n\ts_nop 1" : "=v"(r) : "v"(x));
  return r;
#endif
}
// XOR-swizzled short-index into a [rows][64-short] LDS tile (attn).
__device__ inline int swz(int row, int soff) {
  return (row << 6) + ((((soff >> 3) ^ (row & 7)) << 3) | (soff & 7));
}

#define GLDS(dst, src)                                                        \
  __builtin_amdgcn_global_load_lds(                                           \
      (const __attribute__((address_space(1))) void*)(src),                   \
      (__attribute__((address_space(3))) void*)(dst), 16, 0, 0)

// ---------------- fused cast fp32 -> bf16 (x, w_qkv, w_dense) ----------------
__global__ void cast_all(const float* __restrict__ x, const float* __restrict__ wq,
                         const float* __restrict__ wd, unsigned short* __restrict__ dst) {
  int i = blockIdx.x * blockDim.x + threadIdx.x;  // float4 units
  float4 v;
  if (i < 1048576) v = ((const float4*)x)[i];
  else if (i < 1835008) v = ((const float4*)wq)[i - 1048576];
  else v = ((const float4*)wd)[i - 1835008];
  ushort4 o;
  o.x = f2bf(v.x); o.y = f2bf(v.y); o.z = f2bf(v.z); o.w = f2bf(v.w);
  ((ushort4*)dst)[i] = o;
}

// ---------------- GEMM1 fused: 128x192 tile, BK=64, 512 thr = 8 waves -------
// Verified-best form (35 us): 512 blocks x 80KB dbuf LDS = 2 blocks/CU
// (4 waves/SIMD), one barrier per K-tile, swizzled LDS (0 conflicts),
// VGPR 92 at (512,2) -> no spill. Fused epilogue: rope(q,k); v -> vt.
__global__ __launch_bounds__(512, 2) void gemm_qkv(
    const unsigned short* __restrict__ A, const unsigned short* __restrict__ Bw,
    const float* __restrict__ bias, unsigned short* __restrict__ qkvout,
    unsigned short* __restrict__ vtout,
    const float* __restrict__ fc, const float* __restrict__ fs) {
  const int K = 1024, NT = 16;
  __shared__ __align__(16) unsigned short Ah[2][2][128 * 32];  // 32 KB
  __shared__ __align__(16) unsigned short Bh[2][2][192 * 32];  // 48 KB
  const int tid = threadIdx.x;
  const int w = tid >> 6, l = tid & 63;
  const int lg = l >> 4, lr = l & 15;
  const int wm = w >> 2, wn = w & 3;          // 2m x 4n wave grid
  // XCD-bijective swizzle (nwg = 512, % 8 == 0)
  int id = blockIdx.y * gridDim.x + blockIdx.x;
  const int nwg = gridDim.x * gridDim.y;
  id = (id & 7) * (nwg >> 3) + (id >> 3);
  const int bx = id % gridDim.x, by = id / gridDim.x;
  const int mbase = by * 128, nbase = bx * 192;

  const unsigned short *as0, *bs0, *bs1, *bs2;
  {
    int r_ = tid >> 2, s_ = (tid & 3) ^ ((r_ >> 1) & 3);
    as0 = A + (size_t)(mbase + r_) * K + s_ * 8;
    bs0 = Bw + (size_t)(nbase + r_) * K + s_ * 8;
    int cb2 = 512 + tid;
    int h2 = cb2 >= 768;
    int cw2 = cb2 - h2 * 768;
    int r2 = cw2 >> 2, s2 = (cw2 & 3) ^ ((r2 >> 1) & 3);
    bs1 = Bw + (size_t)(nbase + r2) * K + h2 * 32 + s2 * 8;
    int cw3 = 256 + tid;
    int r3 = cw3 >> 2, s3 = (cw3 & 3) ^ ((r3 >> 1) & 3);
    bs2 = Bw + (size_t)(nbase + r3) * K + 32 + s3 * 8;
  }
#define STAGE(buf, k0)                                                        \
  GLDS(&Ah[buf][0][0] + tid * 8, as0 + (k0));                                 \
  GLDS(&Ah[buf][0][0] + 4096 + tid * 8, as0 + 32 + (k0));                     \
  GLDS(&Bh[buf][0][0] + tid * 8, bs0 + (k0));                                 \
  GLDS(&Bh[buf][0][0] + (512 + tid) * 8, bs1 + (k0));                         \
  GLDS(&Bh[buf][0][0] + (1024 + tid) * 8, bs2 + (k0));

  STAGE(0, 0);
  __syncthreads();

  f32x4 acc[4][3] = {};
  for (int t = 0; t < NT; ++t) {
    const int cur = t & 1;
    if (t + 1 < NT) { STAGE(cur ^ 1, (t + 1) * 64); }
#pragma unroll
    for (int h = 0; h < 2; ++h) {
      bf16x8 bfr[3], af[4];
#pragma unroll
      for (int ni = 0; ni < 3; ++ni) {
        int row = wn * 48 + ni * 16 + lr;
        bfr[ni] = *(const bf16x8*)(&Bh[cur][h][row * 32 + ((lg ^ ((row >> 1) & 3)) << 3)]);
      }
#pragma unroll
      for (int j = 0; j < 4; ++j) {
        int row = wm * 64 + j * 16 + lr;
        af[j] = *(const bf16x8*)(&Ah[cur][h][row * 32 + ((lg ^ ((row >> 1) & 3)) << 3)]);
      }
      __builtin_amdgcn_s_setprio(1);
#pragma unroll
      for (int j = 0; j < 4; ++j)
#pragma unroll
        for (int ni = 0; ni < 3; ++ni)
          acc[j][ni] = __builtin_amdgcn_mfma_f32_16x16x32_bf16(
              af[j], bfr[ni], acc[j][ni], 0, 0, 0);
      __builtin_amdgcn_s_setprio(0);
    }
    __syncthreads();
  }
#undef STAGE

  // ---------------- fused epilogue ----------------
#pragma unroll
  for (int mi = 0; mi < 4; ++mi)
#pragma unroll
    for (int ni = 0; ni < 3; ++ni) {
      int col = nbase + wn * 48 + ni * 16 + lr;
      float bi = bias[col];
      int row0 = mbase + wm * 64 + mi * 16 + lg * 4;
      float o4[4];
#pragma unroll
      for (int r = 0; r < 4; ++r) o4[r] = acc[mi][ni][r] + bi;
      int sect = col >> 10;
      int d = col & 63;
      int srow0 = row0 & 2047;
      if (sect < 2) {
        int p = d >> 1;
#pragma unroll
        for (int r = 0; r < 4; ++r) {
          float vp = __shfl_xor(o4[r], 1);
          float c = fc[(srow0 + r) * 32 + p];
          float s = fs[(srow0 + r) * 32 + p];
          float o = (d & 1) ? (vp * s + o4[r] * c) : (o4[r] * c - vp * s);
          qkvout[(size_t)(row0 + r) * 3072 + col] = f2bf(o);
        }
      } else {
        int bh = (row0 >> 11) * 16 + ((col >> 6) & 15);
        uint2 o;
        o.x = pkcvt(o4[0], o4[1]);
        o.y = pkcvt(o4[2], o4[3]);
        *(uint2*)&vtout[((size_t)(bh * 64 + d)) * 2048 + srow0] = o;
      }
    }
}

// ---------------- GEMM2: 64x128 tile, BK=32, 256 thr = 4 waves (2m x 2n) ----
// 512 blocks (grid 8x64) = 2 blocks/CU: TLP hides the stage drain. Swizzled
// LDS (pre-swizzled global src + linear GLDS dst + swizzled reads).
__global__ __launch_bounds__(256, 2) void gemm_out(
    const unsigned short* __restrict__ A, const unsigned short* __restrict__ Bw,
    const float* __restrict__ bias, float* __restrict__ Cout) {
  const int M = 4096, N = 1024, K = 1024;
  __shared__ __align__(16) unsigned short As[64 * 32];    // 4 KB
  __shared__ __align__(16) unsigned short Bs[128 * 32];   // 8 KB
  const int tid = threadIdx.x;
  const int w = tid >> 6, l = tid & 63;
  const int lg = l >> 4, lr = l & 15;
  const int wm = w >> 1, wn = w & 1;
  // XCD-bijective swizzle (512 blocks, % 8 == 0)
  int id = blockIdx.y * gridDim.x + blockIdx.x;
  const int nwg = gridDim.x * gridDim.y;
  id = (id & 7) * (nwg >> 3) + (id >> 3);
  const int bx = id % gridDim.x, by = id / gridDim.x;
  const int mbase = by * 64, nbase = bx * 128;

  const unsigned short *as0, *bs0, *bs1;
  {
    int r_ = tid >> 2, s_ = (tid & 3) ^ ((r_ >> 1) & 3);
    as0 = A + (size_t)(mbase + r_) * K + s_ * 8;
    bs0 = Bw + (size_t)(nbase + r_) * K + s_ * 8;
    int r2 = 64 + r_, s2 = (tid & 3) ^ ((r2 >> 1) & 3);
    bs1 = Bw + (size_t)(nbase + r2) * K + s2 * 8;
  }

  f32x4 acc[2][4] = {};
  for (int k0 = 0; k0 < K; k0 += 32) {
    GLDS(As + tid * 8, as0 + k0);
    GLDS(Bs + tid * 8, bs0 + k0);
    GLDS(Bs + (256 + tid) * 8, bs1 + k0);
    __syncthreads();
    bf16x8 af[2], bfr[4];
#pragma unroll
    for (int mi = 0; mi < 2; ++mi) {
      int row = wm * 32 + mi * 16 + lr;
      af[mi] = *(const bf16x8*)(As + row * 32 + ((lg ^ ((row >> 1) & 3)) << 3));
    }
#pragma unroll
    for (int ni = 0; ni < 4; ++ni) {
      int row = wn * 64 + ni * 16 + lr;
      bfr[ni] = *(const bf16x8*)(Bs + row * 32 + ((lg ^ ((row >> 1) & 3)) << 3));
    }
    __builtin_amdgcn_s_setprio(1);
#pragma unroll
    for (int mi = 0; mi < 2; ++mi)
#pragma unroll
      for (int ni = 0; ni < 4; ++ni)
        acc[mi][ni] = __builtin_amdgcn_mfma_f32_16x16x32_bf16(
            af[mi], bfr[ni], acc[mi][ni], 0, 0, 0);
    __builtin_amdgcn_s_setprio(0);
    __syncthreads();
  }

#pragma unroll
  for (int mi = 0; mi < 2; ++mi) {
#pragma unroll
    for (int ni = 0; ni < 4; ++ni) {
      int col = nbase + wn * 64 + ni * 16 + lr;
      float bi = bias[col];
#pragma unroll
      for (int r = 0; r < 4; ++r) {
        int row = mbase + wm * 32 + mi * 16 + lg * 4 + r;
        Cout[(size_t)row * N + col] = acc[mi][ni][r] + bi;
      }
    }
  }
}

// ---------------- Flash attention (causal), split-K swapped form ----------------
// Block = (bh, 64 q-rows), 4 waves (256 thr) = 2 q-groups (wq, 32 rows each)
// x 2 k-slices (wk). ka/va LDS reads SHARED across the wave's 2 q-subtiles.
// K/V staged via global_load_lds with PRE-SWIZZLED global source + linear LDS
// dst; 48KB LDS -> 3 blocks/CU; TLP hides stage drain. (Verified best ~36 us.)
__global__ __launch_bounds__(256, 3) void attn(
    const unsigned short* __restrict__ qkv, const unsigned short* __restrict__ vt,
    unsigned short* __restrict__ ctx) {
  __shared__ __align__(16) unsigned short Ks[2][64 * 64];
  __shared__ __align__(16) unsigned short Vs[2][64 * 64];
  __shared__ __align__(16) unsigned short Ps[4][32 * 64];
  int did = blockIdx.x;                  // 1024 blocks
  int x = did & 7, rest = did >> 3;      // XCD x owns bh 4x..4x+3
  int bh = x * 4 + (rest & 3);
  int qi = 31 - (rest >> 2);             // LPT: heavy q-tiles first
  int b = bh >> 4, h = bh & 15;
  int qbase = qi * 64;
  int tid = threadIdx.x;
  int w = tid >> 6, l = tid & 63;
  int lg = l >> 4, lr = l & 15;
  int wq = w & 1, wk = w >> 1;
  int qw = wq * 32;                      // wave's local q base

  // Q fragments for q-rows qbase + qw + mi*16 + lr, log2-domain pre-scale
  bf16x8 qb[2][2];
#pragma unroll
  for (int mi = 0; mi < 2; ++mi)
#pragma unroll
    for (int kc = 0; kc < 2; ++kc) {
      s16x8 qr = *(const s16x8*)(qkv +
          (size_t)(b * Ss + qbase + qw + mi * 16 + lr) * 3072 + h * 64 + kc * 32 + lg * 8);
      bf16x8 qs;
#pragma unroll
      for (int e = 0; e < 8; ++e)
        qs[e] = (__bf16)(bf2f((unsigned short)qr[e]) * 0.18033688f);
      qb[mi][kc] = qs;
    }

  // GLDS staging: thread covers chunks c1=tid, c2=256+tid of each 512-chunk
  // tile; global source pre-swizzled (col = (slot^(row&7))*8), LDS dst linear.
  int c1 = tid, c2 = 256 + tid;
  int r1 = c1 >> 3, s1 = ((c1 & 7) ^ (r1 & 7)) * 8;
  int r2 = c2 >> 3, s2 = ((c2 & 7) ^ (r2 & 7)) * 8;
  const unsigned short* kg1 = qkv + ((size_t)(b * Ss) + r1) * 3072 + 1024 + h * 64 + s1;
  const unsigned short* kg2 = qkv + ((size_t)(b * Ss) + r2) * 3072 + 1024 + h * 64 + s2;
  const unsigned short* vg1 = vt + ((size_t)bh * 64 + r1) * 2048 + s1;
  const unsigned short* vg2 = vt + ((size_t)bh * 64 + r2) * 2048 + s2;
#define STAGEKV(kt)                                                           \
  {                                                                           \
    int tt_ = (kt) & 1;                                                       \
    GLDS(&Ks[tt_][0] + c1 * 8, kg1 + (size_t)(kt) * 64 * 3072);               \
    GLDS(&Ks[tt_][0] + c2 * 8, kg2 + (size_t)(kt) * 64 * 3072);               \
    GLDS(&Vs[tt_][0] + c1 * 8, vg1 + (kt) * 64);                              \
    GLDS(&Vs[tt_][0] + c2 * 8, vg2 + (kt) * 64);                              \
  }

  int nkt = qi + 1;
  int nsup = (nkt + 1) >> 1;

  STAGEKV(0);
  if (1 < nkt) STAGEKV(1);
  __syncthreads();

  f32x4 acc[4][2] = {};       // ctx^T partial: acc[nd][mi], rows d, cols q(=lr)
  float mrow[2] = {-1e30f, -1e30f}, lsum[2] = {0.f, 0.f};

  for (int j = 0; j < nsup; ++j) {
    int kt = 2 * j + wk;
    if (kt < nkt) {
      // S^T = K Q^T (log2-scaled); ka shared across mi
      f32x4 st[4][2] = {};
      __builtin_amdgcn_s_setprio(1);
#pragma unroll
      for (int kc = 0; kc < 2; ++kc) {
#pragma unroll
        for (int ni = 0; ni < 4; ++ni) {
          bf16x8 ka = *(const bf16x8*)&Ks[wk][swz(ni * 16 + lr, kc * 32 + lg * 8)];
#pragma unroll
          for (int mi = 0; mi < 2; ++mi)
            st[ni][mi] = __builtin_amdgcn_mfma_f32_16x16x32_bf16(
                ka, qb[mi][kc], st[ni][mi], 0, 0, 0);
        }
      }
      __builtin_amdgcn_s_setprio(0);

      float tm[2] = {-1e30f, -1e30f};
      if (kt == qi) {               // diagonal tile: causal mask
#pragma unroll
        for (int mi = 0; mi < 2; ++mi) {
          int rq = qw + mi * 16 + lr;
#pragma unroll
          for (int ni = 0; ni < 4; ++ni)
#pragma unroll
            for (int r4 = 0; r4 < 4; ++r4) {
              float s = st[ni][mi][r4];
              if (ni * 16 + lg * 4 + r4 > rq) s = -1e30f;
              st[ni][mi][r4] = s;
              tm[mi] = fmaxf(tm[mi], s);
            }
        }
      } else {
#pragma unroll
        for (int mi = 0; mi < 2; ++mi)
#pragma unroll
          for (int ni = 0; ni < 4; ++ni)
#pragma unroll
            for (int r4 = 0; r4 < 4; ++r4) tm[mi] = fmaxf(tm[mi], st[ni][mi][r4]);
      }
      // defer-max: cross-lane reduce + rescale only when bound trips
      bool ok = (tm[0] <= mrow[0] + 8.0f) && (tm[1] <= mrow[1] + 8.0f);
      if (!__all(ok)) {
#pragma unroll
        for (int mi = 0; mi < 2; ++mi) {
          float t = fmaxf(tm[mi], __shfl_xor(tm[mi], 16));
          t = fmaxf(t, __shfl_xor(t, 32));
          float mnew = fmaxf(mrow[mi], t);
          float alpha = ex2(mrow[mi] - mnew);
          lsum[mi] *= alpha;
#pragma unroll
          for (int nd = 0; nd < 4; ++nd)
#pragma unroll
            for (int r4 = 0; r4 < 4; ++r4) acc[nd][mi][r4] *= alpha;
          mrow[mi] = mnew;
        }
      }
#pragma unroll
      for (int mi = 0; mi < 2; ++mi) {
        float sum = 0.f;
#pragma unroll
        for (int ni = 0; ni < 4; ++ni)
#pragma unroll
          for (int r4 = 0; r4 < 4; ++r4) {
            float pe = ex2(st[ni][mi][r4] - mrow[mi]);
            st[ni][mi][r4] = pe;
            sum += pe;
          }
        lsum[mi] += sum;
        // P[q][k] -> per-wave LDS (swizzled)
#pragma unroll
        for (int ni = 0; ni < 4; ++ni) {
          uint2 wv;
          wv.x = pkcvt(st[ni][mi][0], st[ni][mi][1]);
          wv.y = pkcvt(st[ni][mi][2], st[ni][mi][3]);
          *(uint2*)&Ps[w][swz(mi * 16 + lr, ni * 16 + lg * 4)] = wv;
        }
      }
      // ctx^T += V^T P^T ; va shared across mi
      __builtin_amdgcn_s_setprio(1);
#pragma unroll
      for (int kc = 0; kc < 2; ++kc) {
        bf16x8 pbf[2];
#pragma unroll
        for (int mi = 0; mi < 2; ++mi)
          pbf[mi] = *(const bf16x8*)&Ps[w][swz(mi * 16 + lr, kc * 32 + lg * 8)];
#pragma unroll
        for (int nd = 0; nd < 4; ++nd) {
          bf16x8 va = *(const bf16x8*)&Vs[wk][swz(nd * 16 + lr, kc * 32 + lg * 8)];
#pragma unroll
          for (int mi = 0; mi < 2; ++mi)
            acc[nd][mi] = __builtin_amdgcn_mfma_f32_16x16x32_bf16(
                va, pbf[mi], acc[nd][mi], 0, 0, 0);
        }
      }
      __builtin_amdgcn_s_setprio(0);
    }

    if (j + 1 < nsup) {
      __syncthreads();              // all waves done reading pair j
      int t0 = 2 * (j + 1), t1 = t0 + 1;
      STAGEKV(t0);
      if (t1 < nkt) STAGEKV(t1);
      __syncthreads();              // GLDS drained (compiler vmcnt0 at barrier)
    }
  }
#undef STAGEKV

  // ---- combine the two k-slices of each q-group ----
#pragma unroll
  for (int mi = 0; mi < 2; ++mi) {
    lsum[mi] += __shfl_xor(lsum[mi], 16);
    lsum[mi] += __shfl_xor(lsum[mi], 32);
  }
  __syncthreads();                  // done with K/V; reuse as scratch
  float* aS0 = (float*)Ks;          // [2 wq][64 l][16] = 8KB (mi=0)
  float* aS1 = (float*)Vs;          // mi=1
  float* mlS = (float*)Ps;          // [2 wq][64 l][4]
  if (wk == 1) {
    int base = (wq * 64 + l) * 16;
#pragma unroll
    for (int nd = 0; nd < 4; ++nd) {
      *(f32x4*)(aS0 + base + nd * 4) = acc[nd][0];
      *(f32x4*)(aS1 + base + nd * 4) = acc[nd][1];
    }
    int mb = (wq * 64 + l) * 4;
    mlS[mb] = mrow[0]; mlS[mb + 1] = lsum[0];
    mlS[mb + 2] = mrow[1]; mlS[mb + 3] = lsum[1];
  }
  __syncthreads();
  if (wk == 0) {
    int base = (wq * 64 + l) * 16;
    int mb = (wq * 64 + l) * 4;
#pragma unroll
    for (int mi = 0; mi < 2; ++mi) {
      const float* as = (mi ? aS1 : aS0) + base;
      float m1 = mlS[mb + mi * 2], l1 = mlS[mb + mi * 2 + 1];
      float M = fmaxf(mrow[mi], m1);
      float s0 = ex2(mrow[mi] - M), s1 = ex2(m1 - M);
      float inv = 1.0f / (lsum[mi] * s0 + l1 * s1);
      float f0 = s0 * inv, f1 = s1 * inv;
      int qg = qbase + qw + mi * 16 + lr;
#pragma unroll
      for (int nd = 0; nd < 4; ++nd) {
        f32x4 a1 = *(const f32x4*)(as + nd * 4);
        uint2 o;
        o.x = pkcvt(acc[nd][mi][0] * f0 + a1[0] * f1,
                    acc[nd][mi][1] * f0 + a1[1] * f1);
        o.y = pkcvt(acc[nd][mi][2] * f0 + a1[2] * f1,
                    acc[nd][mi][3] * f0 + a1[3] * f1);
        *(uint2*)&ctx[((size_t)(b * Ss) + qg) * 1024 + h * 64 + nd * 16 + lg * 4] = o;
      }
    }
  }
}

extern "C" void kernel_launch(void* const* d_in, const int* in_sizes, int n_in,
                              void* d_out, int out_size, void* d_ws, size_t ws_size,
                              hipStream_t stream) {
  const float* x       = (const float*)d_in[0];
  const float* w_qkv   = (const float*)d_in[1];
  const float* b_qkv   = (const float*)d_in[2];
  const float* w_dense = (const float*)d_in[3];
  const float* b_dense = (const float*)d_in[4];
  const float* fc      = (const float*)d_in[5];
  const float* fs      = (const float*)d_in[6];
  float* out = (float*)d_out;

  char* ws = (char*)d_ws;
  unsigned short* xb    = (unsigned short*)(ws);                        // 8 MB
  unsigned short* wqkvb = (unsigned short*)(ws + (8ull  << 20));        // 6 MB
  unsigned short* wdb   = (unsigned short*)(ws + (14ull << 20));        // 2 MB
  unsigned short* qkvb  = (unsigned short*)(ws + (16ull << 20));        // 24 MB
  unsigned short* vt    = (unsigned short*)(ws + (40ull << 20));        // 8 MB

  cast_all<<<8192, 256, 0, stream>>>(x, w_qkv, w_dense, xb);

  // GEMM1 fused (128x192 tiles -> 512 blocks = 2/CU, 8 waves, dbuf):
  // rope(q,k) -> qkvb ; v -> vt (transposed)
  gemm_qkv<<<dim3(16, 32), 512, 0, stream>>>(xb, wqkvb, b_qkv, qkvb, vt, fc, fs);
  attn<<<1024, 256, 0, stream>>>(qkvb, vt, xb /* ctx reuse */);
  gemm_out<<<dim3(8, 64), 256, 0, stream>>>(xb, wdb, b_dense, out);
}